// Round 10
// baseline (33.282 us; speedup 1.0000x reference)
//
#include <hip/hip_runtime.h>
#include <math.h>

#define B_    32
#define PPB   256
#define N_    (B_*PPB)     // 8192 proposals / padded slots
#define M_    128
#define LANG_ 256
#define H_    128
#define EPS_  1e-5f
#define MC    16           // columns per MLP block
#define WA_OFF 120832      // byte offset of Wa in workspace (16B aligned)

typedef __attribute__((ext_vector_type(8))) short s16x8;
typedef __attribute__((ext_vector_type(4))) float f32x4;

static __device__ __forceinline__ unsigned short f2bf(float x) {
  unsigned int u = __float_as_uint(x);
  unsigned int r = (u + 0x7fff + ((u >> 16) & 1)) >> 16;
  return (unsigned short)r;
}
static __device__ __forceinline__ float bf2f(unsigned short h) {
  return __uint_as_float(((unsigned int)h) << 16);
}

// ---------------------------------------------------------------------------
// Kernel A (r6 verbatim): batch id + within-chunk stable rank (ballot) +
// chunk histograms + lang projection + frag-major hi/lo bf16 weights Wa.
// Launched TWICE this round as a timing probe (deterministic; srcmap -1
// re-init is ordered before k_scat).
// ---------------------------------------------------------------------------
__global__ __launch_bounds__(256) void k_map_a(
    const int* __restrict__ pidx, const int* __restrict__ poff,
    const int* __restrict__ boff, int* __restrict__ bid_g,
    int* __restrict__ wrank_g, int* __restrict__ hist_g,
    int* __restrict__ src_of_dest,
    const float* __restrict__ Wf, const float* __restrict__ lang,
    float* __restrict__ lp,
    const float* __restrict__ W1, const float* __restrict__ W2,
    unsigned short* __restrict__ wa)
{
  __shared__ int sb[33];
  __shared__ int wh[4][32];
  const int tid = threadIdx.x;
  const int i = blockIdx.x * 256 + tid;
  const int lane = tid & 63, wid = tid >> 6;
  if (tid < 33) sb[tid] = boff[tid];
  __syncthreads();
  const int off = poff[i];
  const int fp  = pidx[2 * off + 1];
  int cnt = 0;
  #pragma unroll
  for (int j = 0; j < 33; ++j) cnt += (sb[j] <= fp) ? 1 : 0;
  int bd = cnt - 1;
  bd = bd < 0 ? 0 : (bd > 31 ? 31 : bd);
  bid_g[i] = bd;
  src_of_dest[i] = -1;

  unsigned long long mym = 0;
  #pragma unroll
  for (int k = 0; k < 32; ++k) {
    const unsigned long long m = __ballot(bd == k);
    if (bd == k) mym = m;
    if (lane == k) wh[wid][k] = __popcll(m);
  }
  const int rw = __popcll(mym & ((1ull << lane) - 1ull));
  __syncthreads();
  int base = 0;
  #pragma unroll
  for (int w = 0; w < 4; ++w) if (w < wid) base += wh[w][bd];
  wrank_g[i] = base + rw;
  if (tid < 32) hist_g[blockIdx.x * 32 + tid] =
      wh[0][tid] + wh[1][tid] + wh[2][tid] + wh[3][tid];

  // lang projection for batch = blockIdx.x: 2 threads per output channel
  {
    const int o = tid >> 1, hf = tid & 1;
    float acc = 0.f;
    const int l0 = hf * 128;
    #pragma unroll 8
    for (int l = l0; l < l0 + 128; l += 4) {
      const float4 w = *reinterpret_cast<const float4*>(Wf + o * 384 + 128 + l);
      const float4 e = *reinterpret_cast<const float4*>(lang + blockIdx.x * LANG_ + l);
      acc += w.x * e.x + w.y * e.y + w.z * e.z + w.w * e.w;
    }
    acc += __shfl_xor(acc, 1);
    if (hf == 0) lp[blockIdx.x * H_ + o] = acc;
  }

  // build Wa: 192 frag-groups over 128 waves
  for (int G = blockIdx.x * 4 + wid; G < 192; G += 128) {
    const int L = G >> 6, s = (G >> 3) & 7, t = G & 7;
    const float* Wsrc; int str;
    if (L == 0)      { Wsrc = Wf; str = 384; }
    else if (L == 1) { Wsrc = W1; str = H_; }
    else             { Wsrc = W2; str = H_; }
    const int o = t * 16 + (lane & 15), g = lane >> 4, sp = s & 3;
    const bool hi = (s < 4);
    const float* rowp = Wsrc + (size_t)o * str + sp * 32 + g * 4;
    const float4 a = *reinterpret_cast<const float4*>(rowp);
    const float4 bq = *reinterpret_cast<const float4*>(rowp + 16);
    const float av[8] = {a.x, a.y, a.z, a.w, bq.x, bq.y, bq.z, bq.w};
    s16x8 v;
    #pragma unroll
    for (int e = 0; e < 8; ++e) {
      const unsigned short h = f2bf(av[e]);
      v[e] = (short)(hi ? h : f2bf(av[e] - bf2f(h)));
    }
    *reinterpret_cast<s16x8*>(wa + (size_t)G * 512 + lane * 8) = v;
  }
}

// ---------------------------------------------------------------------------
// Kernel B (r6 verbatim): parallel per-chunk prefix + scatter inverse map.
// ---------------------------------------------------------------------------
__global__ __launch_bounds__(256) void k_scat(
    const int* __restrict__ bid_g, const int* __restrict__ wrank_g,
    const int* __restrict__ hist_g, int* __restrict__ src_of_dest)
{
  __shared__ int sh[8][32];
  __shared__ int cb[32];
  const int c = blockIdx.x, tid = threadIdx.x;
  const int u = tid >> 5, bin = tid & 31;
  int run = 0;
  #pragma unroll
  for (int p = 0; p < 4; ++p) {
    const int cc = u + 8 * p;
    if (cc < c) run += hist_g[cc * 32 + bin];
  }
  sh[u][bin] = run;
  __syncthreads();
  if (tid < 32) {
    int s = 0;
    #pragma unroll
    for (int w = 0; w < 8; ++w) s += sh[w][tid];
    cb[tid] = s;
  }
  __syncthreads();
  const int i = c * 256 + tid;
  const int bd = bid_g[i];
  const int rank = cb[bd] + wrank_g[i];
  if (rank < PPB) src_of_dest[bd * PPB + rank] = i;   // OOB dropped (.at.set)
}

// ---------------------------------------------------------------------------
// Kernel D (r6 verbatim): MFMA MLP, MC=16, (256,2).
// ---------------------------------------------------------------------------
#define MFMA_LAYER(Aarr)                                                     \
  {                                                                          \
    _Pragma("unroll")                                                        \
    for (int sg = 0; sg < 8; ++sg) {                                         \
      const s16x8 bb = (sg < 4) ? Bh[sg] : Bl[sg - 4];                       \
      acc[0] = __builtin_amdgcn_mfma_f32_16x16x32_bf16(Aarr[0][sg], bb, acc[0], 0, 0, 0); \
      acc[1] = __builtin_amdgcn_mfma_f32_16x16x32_bf16(Aarr[1][sg], bb, acc[1], 0, 0, 0); \
    }                                                                        \
    _Pragma("unroll")                                                        \
    for (int sg = 0; sg < 8; ++sg) {                                         \
      const s16x8 bb = (sg < 4) ? Bl[sg] : Bh[sg - 4];                       \
      acc[0] = __builtin_amdgcn_mfma_f32_16x16x32_bf16(Aarr[0][sg], bb, acc[0], 0, 0, 0); \
      acc[1] = __builtin_amdgcn_mfma_f32_16x16x32_bf16(Aarr[1][sg], bb, acc[1], 0, 0, 0); \
    }                                                                        \
  }

#define READ_B()                                                             \
  {                                                                          \
    _Pragma("unroll")                                                        \
    for (int s = 0; s < 4; ++s) {                                            \
      const int idx = (s * 4 + g) * 16 + o16;                                \
      Bh[s] = XbHi[idx];                                                     \
      Bl[s] = XbLo[idx];                                                     \
    }                                                                        \
  }

#define LOAD_A(Aarr, LL)                                                     \
  {                                                                          \
    _Pragma("unroll")                                                        \
    for (int t = 0; t < 2; ++t)                                              \
      _Pragma("unroll")                                                      \
      for (int s = 0; s < 8; ++s)                                            \
        Aarr[t][s] = *reinterpret_cast<const s16x8*>(                        \
            wa + (size_t)(((LL) * 8 + s) * 8 + (wid * 2 + t)) * 512 + lane * 8); \
  }

__global__ __launch_bounds__(256, 2) void k_mlp(
    const float* __restrict__ feats,
    const unsigned short* __restrict__ wa,
    const float* __restrict__ bf, const float* __restrict__ b1,
    const float* __restrict__ g1, const float* __restrict__ be1,
    const float* __restrict__ rm1, const float* __restrict__ rv1,
    const float* __restrict__ b2, const float* __restrict__ g2,
    const float* __restrict__ be2, const float* __restrict__ rm2,
    const float* __restrict__ rv2,
    const float* __restrict__ W3, const float* __restrict__ b3,
    const int* __restrict__ srcmap, const float* __restrict__ lpg,
    float* __restrict__ out)
{
  __shared__ s16x8 XbHi[256];
  __shared__ s16x8 XbLo[256];
  __shared__ float pbuf[1024];
  __shared__ float outp[64];

  const int tid = threadIdx.x;
  const int lane = tid & 63, wid = tid >> 6;
  const int o16 = lane & 15, g = lane >> 4;
  const int q0 = blockIdx.x * MC;
  const int b = blockIdx.x >> 4;

  s16x8 A0[2][8], A1[2][8], A2[2][8];
  LOAD_A(A0, 0);

  #pragma unroll
  for (int j = tid; j < 1024; j += 256) {
    const int arr = j >> 7, o = j & 127;
    float v;
    switch (arr) {
      case 0: v = bf[o] + lpg[b * H_ + o]; break;
      case 1: v = b1[o]; break;
      case 2: v = g1[o] * rsqrtf(rv1[o] + EPS_); break;
      case 3: { const float s = g1[o] * rsqrtf(rv1[o] + EPS_);
                v = be1[o] - rm1[o] * s; } break;
      case 4: v = b2[o]; break;
      case 5: v = g2[o] * rsqrtf(rv2[o] + EPS_); break;
      case 6: { const float s = g2[o] * rsqrtf(rv2[o] + EPS_);
                v = be2[o] - rm2[o] * s; } break;
      default: v = W3[o]; break;
    }
    pbuf[j] = v;
  }

  {
    const int n = tid & 15, u = tid >> 4;
    const int s = u >> 2, gg = u & 3;
    const int srow = srcmap[q0 + n];
    const int k0 = s * 32 + gg * 4;
    float4 a = make_float4(0.f, 0.f, 0.f, 0.f), bq = a;
    if (srow >= 0) {
      a  = *reinterpret_cast<const float4*>(feats + (size_t)srow * M_ + k0);
      bq = *reinterpret_cast<const float4*>(feats + (size_t)srow * M_ + k0 + 16);
    }
    const float av[8] = {a.x, a.y, a.z, a.w, bq.x, bq.y, bq.z, bq.w};
    s16x8 hv, lv;
    #pragma unroll
    for (int e = 0; e < 8; ++e) {
      const unsigned short h = f2bf(av[e]);
      hv[e] = (short)h;
      lv[e] = (short)f2bf(av[e] - bf2f(h));
    }
    XbHi[u * 16 + n] = hv;
    XbLo[u * 16 + n] = lv;
  }
  __syncthreads();

  f32x4 acc[2];
  s16x8 Bh[4], Bl[4];

  // ================= Layer 0 =================
  READ_B();
  __syncthreads();
  LOAD_A(A1, 1);
  acc[0] = (f32x4){0.f, 0.f, 0.f, 0.f};
  acc[1] = (f32x4){0.f, 0.f, 0.f, 0.f};
  MFMA_LAYER(A0);
  {
    s16x8 hv, lv;
    #pragma unroll
    for (int t = 0; t < 2; ++t)
      #pragma unroll
      for (int r = 0; r < 4; ++r) {
        const int o = (wid * 2 + t) * 16 + g * 4 + r;
        const float v = fmaxf(acc[t][r] + pbuf[o], 0.f);
        const unsigned short h = f2bf(v);
        hv[t * 4 + r] = (short)h;
        lv[t * 4 + r] = (short)f2bf(v - bf2f(h));
      }
    const int widx = (wid * 4 + g) * 16 + o16;
    XbHi[widx] = hv;
    XbLo[widx] = lv;
  }
  __syncthreads();

  // ================= Layer 1 =================
  READ_B();
  __syncthreads();
  LOAD_A(A2, 2);
  acc[0] = (f32x4){0.f, 0.f, 0.f, 0.f};
  acc[1] = (f32x4){0.f, 0.f, 0.f, 0.f};
  MFMA_LAYER(A1);
  {
    s16x8 hv, lv;
    #pragma unroll
    for (int t = 0; t < 2; ++t)
      #pragma unroll
      for (int r = 0; r < 4; ++r) {
        const int o = (wid * 2 + t) * 16 + g * 4 + r;
        const float v = fmaxf(acc[t][r] + pbuf[128 + o], 0.f) * pbuf[256 + o]
                        + pbuf[384 + o];
        const unsigned short h = f2bf(v);
        hv[t * 4 + r] = (short)h;
        lv[t * 4 + r] = (short)f2bf(v - bf2f(h));
      }
    const int widx = (wid * 4 + g) * 16 + o16;
    XbHi[widx] = hv;
    XbLo[widx] = lv;
  }
  __syncthreads();

  // ================= Layer 2 + epilogue =================
  READ_B();
  acc[0] = (f32x4){0.f, 0.f, 0.f, 0.f};
  acc[1] = (f32x4){0.f, 0.f, 0.f, 0.f};
  MFMA_LAYER(A2);
  {
    float p0 = 0.f;
    #pragma unroll
    for (int t = 0; t < 2; ++t)
      #pragma unroll
      for (int r = 0; r < 4; ++r) {
        const int o = (wid * 2 + t) * 16 + g * 4 + r;
        p0 += pbuf[896 + o] *
              (fmaxf(acc[t][r] + pbuf[512 + o], 0.f) * pbuf[640 + o] + pbuf[768 + o]);
      }
    p0 += __shfl_xor(p0, 16);
    p0 += __shfl_xor(p0, 32);
    if (lane < 16) outp[wid * 16 + lane] = p0;
    __syncthreads();
    if (tid < 16)
      out[q0 + tid] = outp[tid] + outp[16 + tid] + outp[32 + tid] + outp[48 + tid] + b3[0];
  }
}

// ---------------------------------------------------------------------------
extern "C" void kernel_launch(void* const* d_in, const int* in_sizes, int n_in,
                              void* d_out, int out_size, void* d_ws, size_t ws_size,
                              hipStream_t stream) {
  const float* feats = (const float*)d_in[0];
  const int*   pidx  = (const int*)d_in[1];
  const int*   poff  = (const int*)d_in[2];
  const int*   boff  = (const int*)d_in[3];
  const float* lang  = (const float*)d_in[4];
  const float* Wf    = (const float*)d_in[5];
  const float* bf    = (const float*)d_in[6];
  const float* W1    = (const float*)d_in[7];
  const float* b1    = (const float*)d_in[8];
  const float* g1    = (const float*)d_in[9];
  const float* be1   = (const float*)d_in[10];
  const float* rm1   = (const float*)d_in[11];
  const float* rv1   = (const float*)d_in[12];
  const float* W2    = (const float*)d_in[13];
  const float* b2    = (const float*)d_in[14];
  const float* g2    = (const float*)d_in[15];
  const float* be2   = (const float*)d_in[16];
  const float* rm2   = (const float*)d_in[17];
  const float* rv2   = (const float*)d_in[18];
  const float* W3    = (const float*)d_in[19];
  const float* b3    = (const float*)d_in[20];
  float* out = (float*)d_out;

  int* srcmap = (int*)d_ws;                  // 32768 B
  int* bidp   = srcmap + N_;                 // 32768 B
  int* wrank  = bidp + N_;                   // 32768 B
  int* hist   = wrank + N_;                  // 4096 B
  float* lp = (float*)(hist + 32 * 32);      // 16384 B
  unsigned short* wa = (unsigned short*)((char*)d_ws + WA_OFF);  // 196608 B

  hipLaunchKernelGGL(k_map_a, dim3(32), dim3(256), 0, stream,
                     pidx, poff, boff, bidp, wrank, hist, srcmap,
                     Wf, lang, lp, W1, W2, wa);
  // ---- timing probe: duplicate k_map_a (deterministic rewrite; srcmap -1
  //      re-init is ordered before k_scat). dur_us - 24.3 = k_map_a + gap.
  hipLaunchKernelGGL(k_map_a, dim3(32), dim3(256), 0, stream,
                     pidx, poff, boff, bidp, wrank, hist, srcmap,
                     Wf, lang, lp, W1, W2, wa);
  hipLaunchKernelGGL(k_scat, dim3(32), dim3(256), 0, stream,
                     bidp, wrank, hist, srcmap);
  hipLaunchKernelGGL(k_mlp, dim3(N_ / MC), dim3(256), 0, stream,
                     feats, wa, bf, b1, g1, be1, rm1, rv1,
                     b2, g2, be2, rm2, rv2, W3, b3, srcmap, lp, out);
}

// Round 11
// 23.307 us; speedup vs baseline: 1.4280x; 1.4280x over previous
//
#include <hip/hip_runtime.h>
#include <math.h>

#define B_    32
#define PPB   256
#define N_    (B_*PPB)     // 8192 proposals / padded slots
#define M_    128
#define LANG_ 256
#define H_    128
#define EPS_  1e-5f
#define MC    16           // columns per MLP block

typedef __attribute__((ext_vector_type(8))) short s16x8;
typedef __attribute__((ext_vector_type(4))) float f32x4;

static __device__ __forceinline__ unsigned short f2bf(float x) {
  unsigned int u = __float_as_uint(x);
  unsigned int r = (u + 0x7fff + ((u >> 16) & 1)) >> 16;
  return (unsigned short)r;
}
static __device__ __forceinline__ float bf2f(unsigned short h) {
  return __uint_as_float(((unsigned int)h) << 16);
}

// ---------------------------------------------------------------------------
// Kernel P: 32 blocks. Block c:
//   - gathers chunk c's 256 first-points from pidx ONCE -> compact fp_c[i]
//   - lang projection for batch c (2 threads/output)
//   - wa build (frag-major hi/lo bf16 weights), 128 wave-slots over 192 groups
// No ranking, no histograms — mapping is derived in k_mlp from fp_c.
// ---------------------------------------------------------------------------
__global__ __launch_bounds__(256) void k_prep(
    const int* __restrict__ pidx, const int* __restrict__ poff,
    int* __restrict__ fp_c,
    const float* __restrict__ Wf, const float* __restrict__ lang,
    float* __restrict__ lp,
    const float* __restrict__ W1, const float* __restrict__ W2,
    unsigned short* __restrict__ wa)
{
  const int tid = threadIdx.x;
  const int lane = tid & 63, wid = tid >> 6;
  const int o16 = lane & 15, g = lane >> 4;
  const int i = blockIdx.x * 256 + tid;

  // ---- compact first-point gather (the ONLY pass over pidx)
  const int off = poff[i];
  fp_c[i] = pidx[2 * off + 1];

  // ---- lang projection for batch = blockIdx.x: 2 threads per output channel
  {
    const int o = tid >> 1, hf = tid & 1;
    float acc = 0.f;
    const int l0 = hf * 128;
    #pragma unroll 8
    for (int l = l0; l < l0 + 128; l += 4) {
      const float4 w = *reinterpret_cast<const float4*>(Wf + o * 384 + 128 + l);
      const float4 e = *reinterpret_cast<const float4*>(lang + blockIdx.x * LANG_ + l);
      acc += w.x * e.x + w.y * e.y + w.z * e.z + w.w * e.w;
    }
    acc += __shfl_xor(acc, 1);
    if (hf == 0) lp[blockIdx.x * H_ + o] = acc;
  }

  // ---- build Wa: 192 frag-groups over 128 wave-slots
  for (int G = blockIdx.x * 4 + wid; G < 192; G += 128) {
    const int L = G >> 6, s = (G >> 3) & 7, t = G & 7;
    const float* Wsrc; int str;
    if (L == 0)      { Wsrc = Wf; str = 384; }
    else if (L == 1) { Wsrc = W1; str = H_; }
    else             { Wsrc = W2; str = H_; }
    const int o = t * 16 + o16, sp = s & 3;
    const bool hi = (s < 4);
    const float* rowp = Wsrc + (size_t)o * str + sp * 32 + g * 4;
    const float4 a = *reinterpret_cast<const float4*>(rowp);
    const float4 bq = *reinterpret_cast<const float4*>(rowp + 16);
    const float av[8] = {a.x, a.y, a.z, a.w, bq.x, bq.y, bq.z, bq.w};
    s16x8 v;
    #pragma unroll
    for (int e = 0; e < 8; ++e) {
      const unsigned short h = f2bf(av[e]);
      v[e] = (short)(hi ? h : f2bf(av[e] - bf2f(h)));
    }
    *reinterpret_cast<s16x8*>(wa + (size_t)G * 512 + lane * 8) = v;
  }
}

// ---------------------------------------------------------------------------
// Kernel D: MFMA MLP + self-contained mapping. 512 blocks x 256 threads
// (2 blocks/CU), 16 cols/block. Each block derives its own 16 srcmap
// entries from the compact fp_c (coalesced int4, L2-hot 32 KB) — no scat
// kernel, no bid/wrank/hist arrays. MLP body = r6 verbatim.
// ---------------------------------------------------------------------------
#define MFMA_LAYER(Aarr)                                                     \
  {                                                                          \
    _Pragma("unroll")                                                        \
    for (int sg = 0; sg < 8; ++sg) {                                         \
      const s16x8 bb = (sg < 4) ? Bh[sg] : Bl[sg - 4];                       \
      acc[0] = __builtin_amdgcn_mfma_f32_16x16x32_bf16(Aarr[0][sg], bb, acc[0], 0, 0, 0); \
      acc[1] = __builtin_amdgcn_mfma_f32_16x16x32_bf16(Aarr[1][sg], bb, acc[1], 0, 0, 0); \
    }                                                                        \
    _Pragma("unroll")                                                        \
    for (int sg = 0; sg < 8; ++sg) {                                         \
      const s16x8 bb = (sg < 4) ? Bl[sg] : Bh[sg - 4];                       \
      acc[0] = __builtin_amdgcn_mfma_f32_16x16x32_bf16(Aarr[0][sg], bb, acc[0], 0, 0, 0); \
      acc[1] = __builtin_amdgcn_mfma_f32_16x16x32_bf16(Aarr[1][sg], bb, acc[1], 0, 0, 0); \
    }                                                                        \
  }

#define READ_B()                                                             \
  {                                                                          \
    _Pragma("unroll")                                                        \
    for (int s = 0; s < 4; ++s) {                                            \
      const int idx = (s * 4 + g) * 16 + o16;                                \
      Bh[s] = XbHi[idx];                                                     \
      Bl[s] = XbLo[idx];                                                     \
    }                                                                        \
  }

#define LOAD_A(Aarr, LL)                                                     \
  {                                                                          \
    _Pragma("unroll")                                                        \
    for (int t = 0; t < 2; ++t)                                              \
      _Pragma("unroll")                                                      \
      for (int s = 0; s < 8; ++s)                                            \
        Aarr[t][s] = *reinterpret_cast<const s16x8*>(                        \
            wa + (size_t)(((LL) * 8 + s) * 8 + (wid * 2 + t)) * 512 + lane * 8); \
  }

__global__ __launch_bounds__(256, 2) void k_mlp(
    const float* __restrict__ feats,
    const unsigned short* __restrict__ wa,
    const int* __restrict__ fp_c, const int* __restrict__ boff,
    const float* __restrict__ bf, const float* __restrict__ b1,
    const float* __restrict__ g1, const float* __restrict__ be1,
    const float* __restrict__ rm1, const float* __restrict__ rv1,
    const float* __restrict__ b2, const float* __restrict__ g2,
    const float* __restrict__ be2, const float* __restrict__ rm2,
    const float* __restrict__ rv2,
    const float* __restrict__ W3, const float* __restrict__ b3,
    const float* __restrict__ lpg,
    float* __restrict__ out)
{
  __shared__ s16x8 XbHi[256];
  __shared__ s16x8 XbLo[256];
  __shared__ float pbuf[1024];
  __shared__ float outp[64];
  __shared__ int   sSrow[MC];
  __shared__ int   wtot[4];

  const int tid = threadIdx.x;
  const int lane = tid & 63, wid = tid >> 6;
  const int o16 = lane & 15, g = lane >> 4;
  const int q0 = blockIdx.x * MC;
  const int b = q0 >> 8;           // 16 blocks per batch
  const int r0 = q0 & 255;         // within-batch column window start

  // ---- derive this block's 16 srcmap entries from compact fp_c
  if (tid < MC) sSrow[tid] = -1;
  const int blo = boff[b], bhi = boff[b + 1];
  const int i0 = tid * 32;
  unsigned mask = 0u;
  #pragma unroll
  for (int jj = 0; jj < 8; ++jj) {
    const int4 pv = *reinterpret_cast<const int4*>(fp_c + i0 + jj * 4);
    const int fps[4] = {pv.x, pv.y, pv.z, pv.w};
    #pragma unroll
    for (int e = 0; e < 4; ++e)
      mask |= (fps[e] >= blo && fps[e] < bhi) ? (1u << (jj * 4 + e)) : 0u;
  }
  const int cnt = __popc(mask);
  int sc = cnt;                    // inclusive wave scan
  #pragma unroll
  for (int d = 1; d < 64; d <<= 1) {
    const int v = __shfl_up(sc, d);
    if (lane >= d) sc += v;
  }
  if (lane == 63) wtot[wid] = sc;
  __syncthreads();                 // sSrow init + wtot visible
  int base = sc - cnt;
  #pragma unroll
  for (int w = 0; w < 4; ++w) if (w < wid) base += wtot[w];
  {
    unsigned m = mask;
    int r = base;
    while (m) {
      const int j = __ffs(m) - 1;
      if (r >= r0 && r < r0 + MC) sSrow[r - r0] = i0 + j;
      ++r;
      m &= m - 1;
    }
  }

  // ---- layer-0 A-frags in flight under pbuf + gather
  s16x8 A0[2][8], A1[2][8], A2[2][8];
  LOAD_A(A0, 0);

  #pragma unroll
  for (int j = tid; j < 1024; j += 256) {
    const int arr = j >> 7, o = j & 127;
    float v;
    switch (arr) {
      case 0: v = bf[o] + lpg[b * H_ + o]; break;
      case 1: v = b1[o]; break;
      case 2: v = g1[o] * rsqrtf(rv1[o] + EPS_); break;
      case 3: { const float s = g1[o] * rsqrtf(rv1[o] + EPS_);
                v = be1[o] - rm1[o] * s; } break;
      case 4: v = b2[o]; break;
      case 5: v = g2[o] * rsqrtf(rv2[o] + EPS_); break;
      case 6: { const float s = g2[o] * rsqrtf(rv2[o] + EPS_);
                v = be2[o] - rm2[o] * s; } break;
      default: v = W3[o]; break;
    }
    pbuf[j] = v;
  }
  __syncthreads();                 // sSrow writes visible

  // ---- gather feats (hi/lo split) into Xb: frag (s,gg) x col n
  {
    const int n = tid & 15, u = tid >> 4;
    const int s = u >> 2, gg = u & 3;
    const int srow = sSrow[n];
    const int k0 = s * 32 + gg * 4;
    float4 a = make_float4(0.f, 0.f, 0.f, 0.f), bq = a;
    if (srow >= 0) {
      a  = *reinterpret_cast<const float4*>(feats + (size_t)srow * M_ + k0);
      bq = *reinterpret_cast<const float4*>(feats + (size_t)srow * M_ + k0 + 16);
    }
    const float av[8] = {a.x, a.y, a.z, a.w, bq.x, bq.y, bq.z, bq.w};
    s16x8 hv, lv;
    #pragma unroll
    for (int e = 0; e < 8; ++e) {
      const unsigned short h = f2bf(av[e]);
      hv[e] = (short)h;
      lv[e] = (short)f2bf(av[e] - bf2f(h));
    }
    XbHi[u * 16 + n] = hv;
    XbLo[u * 16 + n] = lv;
  }
  __syncthreads();

  f32x4 acc[2];
  s16x8 Bh[4], Bl[4];

  // ================= Layer 0 =================
  READ_B();
  __syncthreads();
  LOAD_A(A1, 1);
  acc[0] = (f32x4){0.f, 0.f, 0.f, 0.f};
  acc[1] = (f32x4){0.f, 0.f, 0.f, 0.f};
  MFMA_LAYER(A0);
  {
    s16x8 hv, lv;
    #pragma unroll
    for (int t = 0; t < 2; ++t)
      #pragma unroll
      for (int r = 0; r < 4; ++r) {
        const int o = (wid * 2 + t) * 16 + g * 4 + r;
        const float v = fmaxf(acc[t][r] + pbuf[o], 0.f);
        const unsigned short h = f2bf(v);
        hv[t * 4 + r] = (short)h;
        lv[t * 4 + r] = (short)f2bf(v - bf2f(h));
      }
    const int widx = (wid * 4 + g) * 16 + o16;
    XbHi[widx] = hv;
    XbLo[widx] = lv;
  }
  __syncthreads();

  // ================= Layer 1 =================
  READ_B();
  __syncthreads();
  LOAD_A(A2, 2);
  acc[0] = (f32x4){0.f, 0.f, 0.f, 0.f};
  acc[1] = (f32x4){0.f, 0.f, 0.f, 0.f};
  MFMA_LAYER(A1);
  {
    s16x8 hv, lv;
    #pragma unroll
    for (int t = 0; t < 2; ++t)
      #pragma unroll
      for (int r = 0; r < 4; ++r) {
        const int o = (wid * 2 + t) * 16 + g * 4 + r;
        const float v = fmaxf(acc[t][r] + pbuf[128 + o], 0.f) * pbuf[256 + o]
                        + pbuf[384 + o];
        const unsigned short h = f2bf(v);
        hv[t * 4 + r] = (short)h;
        lv[t * 4 + r] = (short)f2bf(v - bf2f(h));
      }
    const int widx = (wid * 4 + g) * 16 + o16;
    XbHi[widx] = hv;
    XbLo[widx] = lv;
  }
  __syncthreads();

  // ================= Layer 2 + epilogue =================
  READ_B();
  acc[0] = (f32x4){0.f, 0.f, 0.f, 0.f};
  acc[1] = (f32x4){0.f, 0.f, 0.f, 0.f};
  MFMA_LAYER(A2);
  {
    float p0 = 0.f;
    #pragma unroll
    for (int t = 0; t < 2; ++t)
      #pragma unroll
      for (int r = 0; r < 4; ++r) {
        const int o = (wid * 2 + t) * 16 + g * 4 + r;
        p0 += pbuf[896 + o] *
              (fmaxf(acc[t][r] + pbuf[512 + o], 0.f) * pbuf[640 + o] + pbuf[768 + o]);
      }
    p0 += __shfl_xor(p0, 16);
    p0 += __shfl_xor(p0, 32);
    if (lane < 16) outp[wid * 16 + lane] = p0;
    __syncthreads();
    if (tid < 16)
      out[q0 + tid] = outp[tid] + outp[16 + tid] + outp[32 + tid] + outp[48 + tid] + b3[0];
  }
}

// ---------------------------------------------------------------------------
extern "C" void kernel_launch(void* const* d_in, const int* in_sizes, int n_in,
                              void* d_out, int out_size, void* d_ws, size_t ws_size,
                              hipStream_t stream) {
  const float* feats = (const float*)d_in[0];
  const int*   pidx  = (const int*)d_in[1];
  const int*   poff  = (const int*)d_in[2];
  const int*   boff  = (const int*)d_in[3];
  const float* lang  = (const float*)d_in[4];
  const float* Wf    = (const float*)d_in[5];
  const float* bf    = (const float*)d_in[6];
  const float* W1    = (const float*)d_in[7];
  const float* b1    = (const float*)d_in[8];
  const float* g1    = (const float*)d_in[9];
  const float* be1   = (const float*)d_in[10];
  const float* rm1   = (const float*)d_in[11];
  const float* rv1   = (const float*)d_in[12];
  const float* W2    = (const float*)d_in[13];
  const float* b2    = (const float*)d_in[14];
  const float* g2    = (const float*)d_in[15];
  const float* be2   = (const float*)d_in[16];
  const float* rm2   = (const float*)d_in[17];
  const float* rv2   = (const float*)d_in[18];
  const float* W3    = (const float*)d_in[19];
  const float* b3    = (const float*)d_in[20];
  float* out = (float*)d_out;

  int*            fp_c = (int*)d_ws;                               // 32768 B
  float*          lp   = (float*)((char*)d_ws + 32768);            // 16384 B
  unsigned short* wa   = (unsigned short*)((char*)d_ws + 49152);   // 196608 B

  hipLaunchKernelGGL(k_prep, dim3(32), dim3(256), 0, stream,
                     pidx, poff, fp_c, Wf, lang, lp, W1, W2, wa);
  hipLaunchKernelGGL(k_mlp, dim3(N_ / MC), dim3(256), 0, stream,
                     feats, wa, fp_c, boff, bf, b1, g1, be1, rm1, rv1,
                     b2, g2, be2, rm2, rv2, W3, b3, lp, out);
}

// Round 12
// 21.390 us; speedup vs baseline: 1.5560x; 1.0896x over previous
//
#include <hip/hip_runtime.h>
#include <math.h>

#define B_    32
#define PPB   256
#define N_    (B_*PPB)     // 8192 proposals / padded slots
#define M_    128
#define LANG_ 256
#define H_    128
#define EPS_  1e-5f
#define MC    32           // columns per MLP block
#define NBLK  (N_/MC)      // 256 blocks

typedef __attribute__((ext_vector_type(8))) short s16x8;
typedef __attribute__((ext_vector_type(4))) float f32x4;
typedef unsigned long long ull_t;

static __device__ __forceinline__ unsigned short f2bf(float x) {
  unsigned int u = __float_as_uint(x);
  unsigned int r = (u + 0x7fff + ((u >> 16) & 1)) >> 16;
  return (unsigned short)r;
}
static __device__ __forceinline__ float bf2f(unsigned short h) {
  return __uint_as_float(((unsigned int)h) << 16);
}

// ---------------------------------------------------------------------------
// Kernel P (r11 verbatim): 32 blocks. Block c gathers chunk c's first-points
// ONCE -> compact fp_c; lang projection for batch c; wa fragment build.
// ---------------------------------------------------------------------------
__global__ __launch_bounds__(256) void k_prep(
    const int* __restrict__ pidx, const int* __restrict__ poff,
    int* __restrict__ fp_c,
    const float* __restrict__ Wf, const float* __restrict__ lang,
    float* __restrict__ lp,
    const float* __restrict__ W1, const float* __restrict__ W2,
    unsigned short* __restrict__ wa)
{
  const int tid = threadIdx.x;
  const int lane = tid & 63, wid = tid >> 6;
  const int o16 = lane & 15, g = lane >> 4;
  const int i = blockIdx.x * 256 + tid;

  const int off = poff[i];
  fp_c[i] = pidx[2 * off + 1];

  {
    const int o = tid >> 1, hf = tid & 1;
    float acc = 0.f;
    const int l0 = hf * 128;
    #pragma unroll 8
    for (int l = l0; l < l0 + 128; l += 4) {
      const float4 w = *reinterpret_cast<const float4*>(Wf + o * 384 + 128 + l);
      const float4 e = *reinterpret_cast<const float4*>(lang + blockIdx.x * LANG_ + l);
      acc += w.x * e.x + w.y * e.y + w.z * e.z + w.w * e.w;
    }
    acc += __shfl_xor(acc, 1);
    if (hf == 0) lp[blockIdx.x * H_ + o] = acc;
  }

  for (int G = blockIdx.x * 4 + wid; G < 192; G += 128) {
    const int L = G >> 6, s = (G >> 3) & 7, t = G & 7;
    const float* Wsrc; int str;
    if (L == 0)      { Wsrc = Wf; str = 384; }
    else if (L == 1) { Wsrc = W1; str = H_; }
    else             { Wsrc = W2; str = H_; }
    const int o = t * 16 + o16, sp = s & 3;
    const bool hi = (s < 4);
    const float* rowp = Wsrc + (size_t)o * str + sp * 32 + g * 4;
    const float4 a = *reinterpret_cast<const float4*>(rowp);
    const float4 bq = *reinterpret_cast<const float4*>(rowp + 16);
    const float av[8] = {a.x, a.y, a.z, a.w, bq.x, bq.y, bq.z, bq.w};
    s16x8 v;
    #pragma unroll
    for (int e = 0; e < 8; ++e) {
      const unsigned short h = f2bf(av[e]);
      v[e] = (short)(hi ? h : f2bf(av[e] - bf2f(h)));
    }
    *reinterpret_cast<s16x8*>(wa + (size_t)G * 512 + lane * 8) = v;
  }
}

// ---------------------------------------------------------------------------
// Kernel D: MFMA MLP. 256 blocks x 512 threads (8 waves, 1 block/CU,
// 8 waves/CU = r11 occupancy), MC=32 cols/block. Per-block redundant
// traffic halved vs r11 (weights 192KB/block amortized over 2x columns).
// Wave wid owns o-tile wid (16 channels); 2 n-tiles per wave.
// ---------------------------------------------------------------------------
#define LOAD_A(Aarr, LL)                                                     \
  {                                                                          \
    _Pragma("unroll")                                                        \
    for (int s = 0; s < 8; ++s)                                              \
      Aarr[s] = *reinterpret_cast<const s16x8*>(                             \
          wa + (size_t)(((LL) * 8 + s) * 8 + wid) * 512 + lane * 8);         \
  }

#define READ_B()                                                             \
  {                                                                          \
    _Pragma("unroll")                                                        \
    for (int s = 0; s < 4; ++s)                                              \
      _Pragma("unroll")                                                      \
      for (int nt = 0; nt < 2; ++nt) {                                       \
        const int idx = (s * 4 + g) * 32 + nt * 16 + o16;                    \
        Bh[s][nt] = XbHi[idx];                                               \
        Bl[s][nt] = XbLo[idx];                                               \
      }                                                                      \
  }

#define MFMA_LAYER(Aarr)                                                     \
  {                                                                          \
    _Pragma("unroll")                                                        \
    for (int sg = 0; sg < 8; ++sg)                                           \
      _Pragma("unroll")                                                      \
      for (int nt = 0; nt < 2; ++nt) {                                       \
        const s16x8 bb = (sg < 4) ? Bh[sg][nt] : Bl[sg - 4][nt];             \
        acc[nt] = __builtin_amdgcn_mfma_f32_16x16x32_bf16(Aarr[sg], bb, acc[nt], 0, 0, 0); \
      }                                                                      \
    _Pragma("unroll")                                                        \
    for (int sg = 0; sg < 8; ++sg)                                           \
      _Pragma("unroll")                                                      \
      for (int nt = 0; nt < 2; ++nt) {                                       \
        const s16x8 bb = (sg < 4) ? Bl[sg][nt] : Bh[sg - 4][nt];             \
        acc[nt] = __builtin_amdgcn_mfma_f32_16x16x32_bf16(Aarr[sg], bb, acc[nt], 0, 0, 0); \
      }                                                                      \
  }

// activation writeback: wave wid owns channels wid*16 + g*4 + [0,4).
// Frag u = (wid>>1)*4 + g; within-frag half = wid&1 (8B, race-free).
#define ACT_STORE(EXPR_V)                                                    \
  {                                                                          \
    _Pragma("unroll")                                                        \
    for (int nt = 0; nt < 2; ++nt) {                                         \
      ull_t hv64 = 0, lv64 = 0;                                              \
      _Pragma("unroll")                                                      \
      for (int r = 0; r < 4; ++r) {                                          \
        const int o = wid * 16 + g * 4 + r;                                  \
        const float z = acc[nt][r];                                          \
        const float v = (EXPR_V);                                            \
        const unsigned short h = f2bf(v);                                    \
        const unsigned short l = f2bf(v - bf2f(h));                          \
        hv64 |= (ull_t)h << (16 * r);                                        \
        lv64 |= (ull_t)l << (16 * r);                                        \
      }                                                                      \
      const int f = ((wid >> 1) * 4 + g) * 32 + nt * 16 + o16;               \
      reinterpret_cast<ull_t*>(XbHi)[f * 2 + (wid & 1)] = hv64;              \
      reinterpret_cast<ull_t*>(XbLo)[f * 2 + (wid & 1)] = lv64;              \
    }                                                                        \
  }

__global__ __launch_bounds__(512, 2) void k_mlp(
    const float* __restrict__ feats,
    const unsigned short* __restrict__ wa,
    const int* __restrict__ fp_c, const int* __restrict__ boff,
    const float* __restrict__ bf, const float* __restrict__ b1,
    const float* __restrict__ g1, const float* __restrict__ be1,
    const float* __restrict__ rm1, const float* __restrict__ rv1,
    const float* __restrict__ b2, const float* __restrict__ g2,
    const float* __restrict__ be2, const float* __restrict__ rm2,
    const float* __restrict__ rv2,
    const float* __restrict__ W3, const float* __restrict__ b3,
    const float* __restrict__ lpg,
    float* __restrict__ out)
{
  __shared__ s16x8 XbHi[512];      // [u16][n32] frags (8 KB)
  __shared__ s16x8 XbLo[512];      // (8 KB)
  __shared__ float pbuf[1024];     // (4 KB)
  __shared__ float outp[8][32];
  __shared__ int   sSrow[MC];
  __shared__ int   wtot[8];

  const int tid = threadIdx.x;     // 0..511
  const int lane = tid & 63, wid = tid >> 6;   // 8 waves
  const int o16 = lane & 15, g = lane >> 4;
  const int q0 = blockIdx.x * MC;
  const int b = q0 >> 8;           // 8 blocks per batch
  const int r0 = q0 & 255;         // within-batch column window start

  // ---- derive this block's 32 srcmap entries from compact fp_c
  if (tid < MC) sSrow[tid] = -1;
  const int blo = boff[b], bhi = boff[b + 1];
  const int i0 = tid * 16;
  unsigned mask = 0u;
  #pragma unroll
  for (int jj = 0; jj < 4; ++jj) {
    const int4 pv = *reinterpret_cast<const int4*>(fp_c + i0 + jj * 4);
    const int fps[4] = {pv.x, pv.y, pv.z, pv.w};
    #pragma unroll
    for (int e = 0; e < 4; ++e)
      mask |= (fps[e] >= blo && fps[e] < bhi) ? (1u << (jj * 4 + e)) : 0u;
  }
  const int cnt = __popc(mask);
  int sc = cnt;                    // inclusive wave scan
  #pragma unroll
  for (int d = 1; d < 64; d <<= 1) {
    const int v = __shfl_up(sc, d);
    if (lane >= d) sc += v;
  }
  if (lane == 63) wtot[wid] = sc;
  __syncthreads();                 // sSrow init + wtot visible
  int base = sc - cnt;
  #pragma unroll
  for (int w = 0; w < 8; ++w) if (w < wid) base += wtot[w];
  {
    unsigned m = mask;
    int r = base;
    while (m) {
      const int j = __ffs(m) - 1;
      if (r >= r0 && r < r0 + MC) sSrow[r - r0] = i0 + j;
      ++r;
      m &= m - 1;
    }
  }

  // ---- layer-0 A-frags in flight under pbuf + gather
  s16x8 A0[8], A1[8], A2[8];
  LOAD_A(A0, 0);

  #pragma unroll
  for (int j = tid; j < 1024; j += 512) {
    const int arr = j >> 7, o = j & 127;
    float v;
    switch (arr) {
      case 0: v = bf[o] + lpg[b * H_ + o]; break;
      case 1: v = b1[o]; break;
      case 2: v = g1[o] * rsqrtf(rv1[o] + EPS_); break;
      case 3: { const float s = g1[o] * rsqrtf(rv1[o] + EPS_);
                v = be1[o] - rm1[o] * s; } break;
      case 4: v = b2[o]; break;
      case 5: v = g2[o] * rsqrtf(rv2[o] + EPS_); break;
      case 6: { const float s = g2[o] * rsqrtf(rv2[o] + EPS_);
                v = be2[o] - rm2[o] * s; } break;
      default: v = W3[o]; break;
    }
    pbuf[j] = v;
  }
  __syncthreads();                 // sSrow writes visible

  // ---- gather feats (hi/lo split) into Xb: frag u x col n
  {
    const int n = tid & 31, u = tid >> 5;
    const int s = u >> 2, gg = u & 3;
    const int srow = sSrow[n];
    const int k0 = s * 32 + gg * 4;
    float4 a = make_float4(0.f, 0.f, 0.f, 0.f), bq = a;
    if (srow >= 0) {
      a  = *reinterpret_cast<const float4*>(feats + (size_t)srow * M_ + k0);
      bq = *reinterpret_cast<const float4*>(feats + (size_t)srow * M_ + k0 + 16);
    }
    const float av[8] = {a.x, a.y, a.z, a.w, bq.x, bq.y, bq.z, bq.w};
    s16x8 hv, lv;
    #pragma unroll
    for (int e = 0; e < 8; ++e) {
      const unsigned short h = f2bf(av[e]);
      hv[e] = (short)h;
      lv[e] = (short)f2bf(av[e] - bf2f(h));
    }
    XbHi[u * 32 + n] = hv;
    XbLo[u * 32 + n] = lv;
  }
  __syncthreads();

  f32x4 acc[2];
  s16x8 Bh[4][2], Bl[4][2];

  // ================= Layer 0 =================
  READ_B();
  __syncthreads();
  LOAD_A(A1, 1);
  acc[0] = (f32x4){0.f, 0.f, 0.f, 0.f};
  acc[1] = (f32x4){0.f, 0.f, 0.f, 0.f};
  MFMA_LAYER(A0);
  ACT_STORE(fmaxf(z + pbuf[o], 0.f));
  __syncthreads();

  // ================= Layer 1 =================
  READ_B();
  __syncthreads();
  LOAD_A(A2, 2);
  acc[0] = (f32x4){0.f, 0.f, 0.f, 0.f};
  acc[1] = (f32x4){0.f, 0.f, 0.f, 0.f};
  MFMA_LAYER(A1);
  ACT_STORE(fmaxf(z + pbuf[128 + o], 0.f) * pbuf[256 + o] + pbuf[384 + o]);
  __syncthreads();

  // ================= Layer 2 + epilogue =================
  READ_B();
  acc[0] = (f32x4){0.f, 0.f, 0.f, 0.f};
  acc[1] = (f32x4){0.f, 0.f, 0.f, 0.f};
  MFMA_LAYER(A2);
  {
    float p0 = 0.f, p1 = 0.f;
    #pragma unroll
    for (int r = 0; r < 4; ++r) {
      const int o = wid * 16 + g * 4 + r;
      const float w3 = pbuf[896 + o];
      const float bb2 = pbuf[512 + o], ss2 = pbuf[640 + o], tt2 = pbuf[768 + o];
      p0 += w3 * (fmaxf(acc[0][r] + bb2, 0.f) * ss2 + tt2);
      p1 += w3 * (fmaxf(acc[1][r] + bb2, 0.f) * ss2 + tt2);
    }
    p0 += __shfl_xor(p0, 16); p0 += __shfl_xor(p0, 32);
    p1 += __shfl_xor(p1, 16); p1 += __shfl_xor(p1, 32);
    if (lane < 16) {
      outp[wid][o16] = p0;
      outp[wid][16 + o16] = p1;
    }
    __syncthreads();
    if (tid < 32) {
      float s = b3[0];
      #pragma unroll
      for (int w = 0; w < 8; ++w) s += outp[w][tid];
      out[q0 + tid] = s;
    }
  }
}

// ---------------------------------------------------------------------------
extern "C" void kernel_launch(void* const* d_in, const int* in_sizes, int n_in,
                              void* d_out, int out_size, void* d_ws, size_t ws_size,
                              hipStream_t stream) {
  const float* feats = (const float*)d_in[0];
  const int*   pidx  = (const int*)d_in[1];
  const int*   poff  = (const int*)d_in[2];
  const int*   boff  = (const int*)d_in[3];
  const float* lang  = (const float*)d_in[4];
  const float* Wf    = (const float*)d_in[5];
  const float* bf    = (const float*)d_in[6];
  const float* W1    = (const float*)d_in[7];
  const float* b1    = (const float*)d_in[8];
  const float* g1    = (const float*)d_in[9];
  const float* be1   = (const float*)d_in[10];
  const float* rm1   = (const float*)d_in[11];
  const float* rv1   = (const float*)d_in[12];
  const float* W2    = (const float*)d_in[13];
  const float* b2    = (const float*)d_in[14];
  const float* g2    = (const float*)d_in[15];
  const float* be2   = (const float*)d_in[16];
  const float* rm2   = (const float*)d_in[17];
  const float* rv2   = (const float*)d_in[18];
  const float* W3    = (const float*)d_in[19];
  const float* b3    = (const float*)d_in[20];
  float* out = (float*)d_out;

  int*            fp_c = (int*)d_ws;                               // 32768 B
  float*          lp   = (float*)((char*)d_ws + 32768);            // 16384 B
  unsigned short* wa   = (unsigned short*)((char*)d_ws + 49152);   // 196608 B

  hipLaunchKernelGGL(k_prep, dim3(32), dim3(256), 0, stream,
                     pidx, poff, fp_c, Wf, lang, lp, W1, W2, wa);
  hipLaunchKernelGGL(k_mlp, dim3(NBLK), dim3(512), 0, stream,
                     feats, wa, fp_c, boff, bf, b1, g1, be1, rm1, rv1,
                     b2, g2, be2, rm2, rv2, W3, b3, lp, out);
}

// Round 13
// 20.563 us; speedup vs baseline: 1.6185x; 1.0402x over previous
//
#include <hip/hip_runtime.h>
#include <math.h>

#define B_    32
#define PPB   256
#define N_    (B_*PPB)     // 8192 proposals / padded slots
#define M_    128
#define LANG_ 256
#define H_    128
#define EPS_  1e-5f
#define MC    32           // columns per MLP block
#define NBLK  (N_/MC)      // 256 blocks

typedef __attribute__((ext_vector_type(8))) short s16x8;
typedef __attribute__((ext_vector_type(4))) float f32x4;
typedef unsigned long long ull_t;

static __device__ __forceinline__ unsigned short f2bf(float x) {
  unsigned int u = __float_as_uint(x);
  unsigned int r = (u + 0x7fff + ((u >> 16) & 1)) >> 16;
  return (unsigned short)r;
}
static __device__ __forceinline__ float bf2f(unsigned short h) {
  return __uint_as_float(((unsigned int)h) << 16);
}

// ---------------------------------------------------------------------------
// Kernel P: 96 blocks, three DISJOINT roles running in parallel:
//   blk  0-31: fp_c gather for chunk blk (1 scattered load/thread; the
//              critical path for k_mlp's dependency)
//   blk 32-63: lang projection for batch blk-32 (2 threads/output)
//   blk 64-95: wa build (frag-major hi/lo bf16 weights), 6 groups/block
// Makespan = max(roles) instead of sum of serial phases.
// ---------------------------------------------------------------------------
__global__ __launch_bounds__(256) void k_prep(
    const int* __restrict__ pidx, const int* __restrict__ poff,
    int* __restrict__ fp_c,
    const float* __restrict__ Wf, const float* __restrict__ lang,
    float* __restrict__ lp,
    const float* __restrict__ W1, const float* __restrict__ W2,
    unsigned short* __restrict__ wa)
{
  const int tid = threadIdx.x;
  const int lane = tid & 63, wid = tid >> 6;
  const int o16 = lane & 15, g = lane >> 4;
  const int blk = blockIdx.x;

  if (blk < 32) {
    // ---- compact first-point gather (the ONLY pass over pidx)
    const int i = blk * 256 + tid;
    const int off = poff[i];
    fp_c[i] = pidx[2 * off + 1];
  } else if (blk < 64) {
    // ---- lang projection for batch blk-32: 2 threads per output channel
    const int bb = blk - 32;
    const int o = tid >> 1, hf = tid & 1;
    float acc = 0.f;
    const int l0 = hf * 128;
    #pragma unroll 8
    for (int l = l0; l < l0 + 128; l += 4) {
      const float4 w = *reinterpret_cast<const float4*>(Wf + o * 384 + 128 + l);
      const float4 e = *reinterpret_cast<const float4*>(lang + bb * LANG_ + l);
      acc += w.x * e.x + w.y * e.y + w.z * e.z + w.w * e.w;
    }
    acc += __shfl_xor(acc, 1);
    if (hf == 0) lp[bb * H_ + o] = acc;
  } else {
    // ---- wa build: 6 frag-groups per block (G = 0..191)
    for (int sub = wid; sub < 6; sub += 4) {
      const int G = (blk - 64) * 6 + sub;
      const int L = G >> 6, s = (G >> 3) & 7, t = G & 7;
      const float* Wsrc; int str;
      if (L == 0)      { Wsrc = Wf; str = 384; }
      else if (L == 1) { Wsrc = W1; str = H_; }
      else             { Wsrc = W2; str = H_; }
      const int o = t * 16 + o16, sp = s & 3;
      const bool hi = (s < 4);
      const float* rowp = Wsrc + (size_t)o * str + sp * 32 + g * 4;
      const float4 a = *reinterpret_cast<const float4*>(rowp);
      const float4 bq = *reinterpret_cast<const float4*>(rowp + 16);
      const float av[8] = {a.x, a.y, a.z, a.w, bq.x, bq.y, bq.z, bq.w};
      s16x8 v;
      #pragma unroll
      for (int e = 0; e < 8; ++e) {
        const unsigned short h = f2bf(av[e]);
        v[e] = (short)(hi ? h : f2bf(av[e] - bf2f(h)));
      }
      *reinterpret_cast<s16x8*>(wa + (size_t)G * 512 + lane * 8) = v;
    }
  }
}

// ---------------------------------------------------------------------------
// Kernel D (r12 verbatim): MFMA MLP. 256 blocks x 512 threads (8 waves,
// 1 block/CU, 8 waves/CU), MC=32 cols/block. Wave wid owns o-tile wid.
// ---------------------------------------------------------------------------
#define LOAD_A(Aarr, LL)                                                     \
  {                                                                          \
    _Pragma("unroll")                                                        \
    for (int s = 0; s < 8; ++s)                                              \
      Aarr[s] = *reinterpret_cast<const s16x8*>(                             \
          wa + (size_t)(((LL) * 8 + s) * 8 + wid) * 512 + lane * 8);         \
  }

#define READ_B()                                                             \
  {                                                                          \
    _Pragma("unroll")                                                        \
    for (int s = 0; s < 4; ++s)                                              \
      _Pragma("unroll")                                                      \
      for (int nt = 0; nt < 2; ++nt) {                                       \
        const int idx = (s * 4 + g) * 32 + nt * 16 + o16;                    \
        Bh[s][nt] = XbHi[idx];                                               \
        Bl[s][nt] = XbLo[idx];                                               \
      }                                                                      \
  }

#define MFMA_LAYER(Aarr)                                                     \
  {                                                                          \
    _Pragma("unroll")                                                        \
    for (int sg = 0; sg < 8; ++sg)                                           \
      _Pragma("unroll")                                                      \
      for (int nt = 0; nt < 2; ++nt) {                                       \
        const s16x8 bb = (sg < 4) ? Bh[sg][nt] : Bl[sg - 4][nt];             \
        acc[nt] = __builtin_amdgcn_mfma_f32_16x16x32_bf16(Aarr[sg], bb, acc[nt], 0, 0, 0); \
      }                                                                      \
    _Pragma("unroll")                                                        \
    for (int sg = 0; sg < 8; ++sg)                                           \
      _Pragma("unroll")                                                      \
      for (int nt = 0; nt < 2; ++nt) {                                       \
        const s16x8 bb = (sg < 4) ? Bl[sg][nt] : Bh[sg - 4][nt];             \
        acc[nt] = __builtin_amdgcn_mfma_f32_16x16x32_bf16(Aarr[sg], bb, acc[nt], 0, 0, 0); \
      }                                                                      \
  }

#define ACT_STORE(EXPR_V)                                                    \
  {                                                                          \
    _Pragma("unroll")                                                        \
    for (int nt = 0; nt < 2; ++nt) {                                         \
      ull_t hv64 = 0, lv64 = 0;                                              \
      _Pragma("unroll")                                                      \
      for (int r = 0; r < 4; ++r) {                                          \
        const int o = wid * 16 + g * 4 + r;                                  \
        const float z = acc[nt][r];                                          \
        const float v = (EXPR_V);                                            \
        const unsigned short h = f2bf(v);                                    \
        const unsigned short l = f2bf(v - bf2f(h));                          \
        hv64 |= (ull_t)h << (16 * r);                                        \
        lv64 |= (ull_t)l << (16 * r);                                        \
      }                                                                      \
      const int f = ((wid >> 1) * 4 + g) * 32 + nt * 16 + o16;               \
      reinterpret_cast<ull_t*>(XbHi)[f * 2 + (wid & 1)] = hv64;              \
      reinterpret_cast<ull_t*>(XbLo)[f * 2 + (wid & 1)] = lv64;              \
    }                                                                        \
  }

__global__ __launch_bounds__(512, 2) void k_mlp(
    const float* __restrict__ feats,
    const unsigned short* __restrict__ wa,
    const int* __restrict__ fp_c, const int* __restrict__ boff,
    const float* __restrict__ bf, const float* __restrict__ b1,
    const float* __restrict__ g1, const float* __restrict__ be1,
    const float* __restrict__ rm1, const float* __restrict__ rv1,
    const float* __restrict__ b2, const float* __restrict__ g2,
    const float* __restrict__ be2, const float* __restrict__ rm2,
    const float* __restrict__ rv2,
    const float* __restrict__ W3, const float* __restrict__ b3,
    const float* __restrict__ lpg,
    float* __restrict__ out)
{
  __shared__ s16x8 XbHi[512];      // [u16][n32] frags (8 KB)
  __shared__ s16x8 XbLo[512];      // (8 KB)
  __shared__ float pbuf[1024];     // (4 KB)
  __shared__ float outp[8][32];
  __shared__ int   sSrow[MC];
  __shared__ int   wtot[8];

  const int tid = threadIdx.x;     // 0..511
  const int lane = tid & 63, wid = tid >> 6;   // 8 waves
  const int o16 = lane & 15, g = lane >> 4;
  const int q0 = blockIdx.x * MC;
  const int b = q0 >> 8;           // 8 blocks per batch
  const int r0 = q0 & 255;         // within-batch column window start

  // ---- derive this block's 32 srcmap entries from compact fp_c
  if (tid < MC) sSrow[tid] = -1;
  const int blo = boff[b], bhi = boff[b + 1];
  const int i0 = tid * 16;
  unsigned mask = 0u;
  #pragma unroll
  for (int jj = 0; jj < 4; ++jj) {
    const int4 pv = *reinterpret_cast<const int4*>(fp_c + i0 + jj * 4);
    const int fps[4] = {pv.x, pv.y, pv.z, pv.w};
    #pragma unroll
    for (int e = 0; e < 4; ++e)
      mask |= (fps[e] >= blo && fps[e] < bhi) ? (1u << (jj * 4 + e)) : 0u;
  }
  const int cnt = __popc(mask);
  int sc = cnt;                    // inclusive wave scan
  #pragma unroll
  for (int d = 1; d < 64; d <<= 1) {
    const int v = __shfl_up(sc, d);
    if (lane >= d) sc += v;
  }
  if (lane == 63) wtot[wid] = sc;
  __syncthreads();                 // sSrow init + wtot visible
  int base = sc - cnt;
  #pragma unroll
  for (int w = 0; w < 8; ++w) if (w < wid) base += wtot[w];
  {
    unsigned m = mask;
    int r = base;
    while (m) {
      const int j = __ffs(m) - 1;
      if (r >= r0 && r < r0 + MC) sSrow[r - r0] = i0 + j;
      ++r;
      m &= m - 1;
    }
  }

  // ---- layer-0 A-frags in flight under pbuf + gather
  s16x8 A0[8], A1[8], A2[8];
  LOAD_A(A0, 0);

  #pragma unroll
  for (int j = tid; j < 1024; j += 512) {
    const int arr = j >> 7, o = j & 127;
    float v;
    switch (arr) {
      case 0: v = bf[o] + lpg[b * H_ + o]; break;
      case 1: v = b1[o]; break;
      case 2: v = g1[o] * rsqrtf(rv1[o] + EPS_); break;
      case 3: { const float s = g1[o] * rsqrtf(rv1[o] + EPS_);
                v = be1[o] - rm1[o] * s; } break;
      case 4: v = b2[o]; break;
      case 5: v = g2[o] * rsqrtf(rv2[o] + EPS_); break;
      case 6: { const float s = g2[o] * rsqrtf(rv2[o] + EPS_);
                v = be2[o] - rm2[o] * s; } break;
      default: v = W3[o]; break;
    }
    pbuf[j] = v;
  }
  __syncthreads();                 // sSrow writes visible

  // ---- gather feats (hi/lo split) into Xb: frag u x col n
  {
    const int n = tid & 31, u = tid >> 5;
    const int s = u >> 2, gg = u & 3;
    const int srow = sSrow[n];
    const int k0 = s * 32 + gg * 4;
    float4 a = make_float4(0.f, 0.f, 0.f, 0.f), bq = a;
    if (srow >= 0) {
      a  = *reinterpret_cast<const float4*>(feats + (size_t)srow * M_ + k0);
      bq = *reinterpret_cast<const float4*>(feats + (size_t)srow * M_ + k0 + 16);
    }
    const float av[8] = {a.x, a.y, a.z, a.w, bq.x, bq.y, bq.z, bq.w};
    s16x8 hv, lv;
    #pragma unroll
    for (int e = 0; e < 8; ++e) {
      const unsigned short h = f2bf(av[e]);
      hv[e] = (short)h;
      lv[e] = (short)f2bf(av[e] - bf2f(h));
    }
    XbHi[u * 32 + n] = hv;
    XbLo[u * 32 + n] = lv;
  }
  __syncthreads();

  f32x4 acc[2];
  s16x8 Bh[4][2], Bl[4][2];

  // ================= Layer 0 =================
  READ_B();
  __syncthreads();
  LOAD_A(A1, 1);
  acc[0] = (f32x4){0.f, 0.f, 0.f, 0.f};
  acc[1] = (f32x4){0.f, 0.f, 0.f, 0.f};
  MFMA_LAYER(A0);
  ACT_STORE(fmaxf(z + pbuf[o], 0.f));
  __syncthreads();

  // ================= Layer 1 =================
  READ_B();
  __syncthreads();
  LOAD_A(A2, 2);
  acc[0] = (f32x4){0.f, 0.f, 0.f, 0.f};
  acc[1] = (f32x4){0.f, 0.f, 0.f, 0.f};
  MFMA_LAYER(A1);
  ACT_STORE(fmaxf(z + pbuf[128 + o], 0.f) * pbuf[256 + o] + pbuf[384 + o]);
  __syncthreads();

  // ================= Layer 2 + epilogue =================
  READ_B();
  acc[0] = (f32x4){0.f, 0.f, 0.f, 0.f};
  acc[1] = (f32x4){0.f, 0.f, 0.f, 0.f};
  MFMA_LAYER(A2);
  {
    float p0 = 0.f, p1 = 0.f;
    #pragma unroll
    for (int r = 0; r < 4; ++r) {
      const int o = wid * 16 + g * 4 + r;
      const float w3 = pbuf[896 + o];
      const float bb2 = pbuf[512 + o], ss2 = pbuf[640 + o], tt2 = pbuf[768 + o];
      p0 += w3 * (fmaxf(acc[0][r] + bb2, 0.f) * ss2 + tt2);
      p1 += w3 * (fmaxf(acc[1][r] + bb2, 0.f) * ss2 + tt2);
    }
    p0 += __shfl_xor(p0, 16); p0 += __shfl_xor(p0, 32);
    p1 += __shfl_xor(p1, 16); p1 += __shfl_xor(p1, 32);
    if (lane < 16) {
      outp[wid][o16] = p0;
      outp[wid][16 + o16] = p1;
    }
    __syncthreads();
    if (tid < 32) {
      float s = b3[0];
      #pragma unroll
      for (int w = 0; w < 8; ++w) s += outp[w][tid];
      out[q0 + tid] = s;
    }
  }
}

// ---------------------------------------------------------------------------
extern "C" void kernel_launch(void* const* d_in, const int* in_sizes, int n_in,
                              void* d_out, int out_size, void* d_ws, size_t ws_size,
                              hipStream_t stream) {
  const float* feats = (const float*)d_in[0];
  const int*   pidx  = (const int*)d_in[1];
  const int*   poff  = (const int*)d_in[2];
  const int*   boff  = (const int*)d_in[3];
  const float* lang  = (const float*)d_in[4];
  const float* Wf    = (const float*)d_in[5];
  const float* bf    = (const float*)d_in[6];
  const float* W1    = (const float*)d_in[7];
  const float* b1    = (const float*)d_in[8];
  const float* g1    = (const float*)d_in[9];
  const float* be1   = (const float*)d_in[10];
  const float* rm1   = (const float*)d_in[11];
  const float* rv1   = (const float*)d_in[12];
  const float* W2    = (const float*)d_in[13];
  const float* b2    = (const float*)d_in[14];
  const float* g2    = (const float*)d_in[15];
  const float* be2   = (const float*)d_in[16];
  const float* rm2   = (const float*)d_in[17];
  const float* rv2   = (const float*)d_in[18];
  const float* W3    = (const float*)d_in[19];
  const float* b3    = (const float*)d_in[20];
  float* out = (float*)d_out;

  int*            fp_c = (int*)d_ws;                               // 32768 B
  float*          lp   = (float*)((char*)d_ws + 32768);            // 16384 B
  unsigned short* wa   = (unsigned short*)((char*)d_ws + 49152);   // 196608 B

  hipLaunchKernelGGL(k_prep, dim3(96), dim3(256), 0, stream,
                     pidx, poff, fp_c, Wf, lang, lp, W1, W2, wa);
  hipLaunchKernelGGL(k_mlp, dim3(NBLK), dim3(512), 0, stream,
                     feats, wa, fp_c, boff, bf, b1, g1, be1, rm1, rv1,
                     b2, g2, be2, rm2, rv2, W3, b3, lp, out);
}